// Round 2
// baseline (116.853 us; speedup 1.0000x reference)
//
#include <hip/hip_runtime.h>
#include <hip/hip_bf16.h>

#define BB 16
#define LL 1444
#define DD 128
#define CC 21
#define CH 38   // chunk length
#define NK 38   // number of chunks; CH*NK == LL

#define CS_ELEMS ((size_t)BB*NK*CC*DD)
#define TOT_ELEMS ((size_t)BB*CC*DD)

// K1: per-chunk per-class partial sums of source (fp32), plus the source copy
// into the second half of d_out.
__global__ __launch_bounds__(128) void k1_chunk_sums(
    const float* __restrict__ src, const int* __restrict__ idx,
    float* __restrict__ cs, float* __restrict__ src_copy)
{
  int blk = blockIdx.x;
  int b = blk / NK, k = blk % NK;
  int d = threadIdx.x;
  int i0 = k * CH;
  float acc[CC];
#pragma unroll
  for (int c = 0; c < CC; ++c) acc[c] = 0.f;
  const int* idxb = idx + b * LL;
  for (int t = 0; t < CH; ++t) {
    int i = i0 + t;
    int ci = idxb[i];
    size_t off = ((size_t)(b * LL + i)) * DD + d;
    float v = src[off];
    src_copy[off] = v;
#pragma unroll
    for (int c = 0; c < CC; ++c) acc[c] += (ci == c) ? v : 0.f;
  }
  float* o = cs + ((size_t)(b * NK + k)) * CC * DD + d;
#pragma unroll
  for (int c = 0; c < CC; ++c) o[c * DD] = acc[c];
}

// K2: exclusive scan over chunks for each (b, c); in-place on cs; writes totals.
__global__ __launch_bounds__(128) void k2_scan(
    float* __restrict__ cs, float* __restrict__ tot)
{
  int b = blockIdx.x / CC, c = blockIdx.x % CC;
  int d = threadIdx.x;
  float run = 0.f;
  for (int k = 0; k < NK; ++k) {
    size_t off = (((size_t)(b * NK + k)) * CC + c) * DD + d;
    float t = cs[off];
    cs[off] = run;   // exclusive prefix of chunk sums
    run += t;
  }
  tot[((size_t)(b * CC + c)) * DD + d] = run;
}

// K3: R[b][a][d] = sum_c P[c][a] * Tot[b][c][d]
__global__ __launch_bounds__(128) void k3_R(
    const float* __restrict__ P, const float* __restrict__ tot,
    float* __restrict__ R)
{
  int b = blockIdx.x / CC, a = blockIdx.x % CC;
  int d = threadIdx.x;
  float r = 0.f;
#pragma unroll
  for (int c = 0; c < CC; ++c)
    r += P[c * CC + a] * tot[((size_t)(b * CC + c)) * DD + d];
  R[((size_t)(b * CC + a)) * DD + d] = r;
}

// K4: within-chunk sequential scan producing fused.
// fused[i] = sum_c Q[c_i][c]*Pre_c(i) + R[c_i] + ((c_i!=0)-P[c_i][c_i])*src[i]
__global__ __launch_bounds__(128) void k4_fused(
    const float* __restrict__ src, const int* __restrict__ idx,
    const float* __restrict__ P, const float* __restrict__ cs,
    const float* __restrict__ R, float* __restrict__ out)
{
  __shared__ float Qs[CC * CC];
  __shared__ float Ss[CC];
  int b = blockIdx.x / NK, k = blockIdx.x % NK;
  int d = threadIdx.x;

  for (int t = threadIdx.x; t < CC * CC; t += blockDim.x) {
    int a = t / CC, c = t % CC;
    Qs[t] = P[a * CC + c] - P[c * CC + a];
  }
  if (threadIdx.x < CC) {
    int a = threadIdx.x;
    Ss[a] = (a != 0 ? 1.0f : 0.0f) - P[a * CC + a];
  }
  __syncthreads();

  float pre[CC];
  const float* csb = cs + ((size_t)(b * NK + k)) * CC * DD + d;
#pragma unroll
  for (int c = 0; c < CC; ++c) pre[c] = csb[c * DD];

  int i0 = k * CH;
  const int* idxb = idx + b * LL;
  for (int t = 0; t < CH; ++t) {
    int i = i0 + t;
    int ci = idxb[i];
    size_t off = ((size_t)(b * LL + i)) * DD + d;
    float v = src[off];
    float acc = R[((size_t)(b * CC + ci)) * DD + d] + Ss[ci] * v;
    const float* q = &Qs[ci * CC];
#pragma unroll
    for (int c = 0; c < CC; ++c) acc += q[c] * pre[c];
    out[off] = acc;
#pragma unroll
    for (int c = 0; c < CC; ++c) pre[c] += (ci == c) ? v : 0.f;
  }
}

extern "C" void kernel_launch(void* const* d_in, const int* in_sizes, int n_in,
                              void* d_out, int out_size, void* d_ws, size_t ws_size,
                              hipStream_t stream) {
  const float* P   = (const float*)d_in[0];   // cls_r_prob (C*C)
  const float* src = (const float*)d_in[1];   // source (B*L*D)
  const int*   idx = (const int*)d_in[2];     // class_idx (B*L)

  float* out_fused = (float*)d_out;                      // first B*L*D
  float* out_src   = out_fused + (size_t)BB * LL * DD;   // second B*L*D

  float* cs  = (float*)d_ws;           // [B][NK][C][D]
  float* tot = cs + CS_ELEMS;          // [B][C][D]
  float* R   = tot + TOT_ELEMS;        // [B][C][D]

  k1_chunk_sums<<<BB * NK, 128, 0, stream>>>(src, idx, cs, out_src);
  k2_scan<<<BB * CC, 128, 0, stream>>>(cs, tot);
  k3_R<<<BB * CC, 128, 0, stream>>>(P, tot, R);
  k4_fused<<<BB * NK, 128, 0, stream>>>(src, idx, P, cs, R, out_fused);
}